// Round 5
// baseline (98.523 us; speedup 1.0000x reference)
//
#include <hip/hip_runtime.h>
#include <math.h>

// Problem constants (from reference: N=512, D=4096, fp32).
#define PN 512
#define PD 4096

// ws float-index layout:
//   [0,512) sa | [512,1024) sp | [1024,1536) dd
//   1536 sum(f32) | 1537 cnt(u32) | 1538 done(u32)
//   byte 8192:      ah bf16 [512][4096]  (4 MB)
//   byte 8192+4MB:  ph bf16 [512][4096]  (4 MB)
#define F_SA 0
#define F_SP 512
#define F_DD 1024
#define F_SUM 1536
#define F_CNT 1537
#define F_DONE 1538
#define WS_AH_BYTES 8192
#define WS_PH_BYTES (8192 + 4194304)
#define WS_NEED ((size_t)(8192 + 2 * 4194304))

typedef __attribute__((ext_vector_type(8))) short short8;
typedef __attribute__((ext_vector_type(4))) float floatx4;

static __device__ __forceinline__ unsigned short f2bf(float x) {
    unsigned int u = __float_as_uint(x);
    u += 0x7fffu + ((u >> 16) & 1u);
    return (unsigned short)(u >> 16);
}

static __device__ __forceinline__ void load16_lds(const void* gp, void* lp) {
    __builtin_amdgcn_global_load_lds(
        (const __attribute__((address_space(1))) unsigned int*)gp,
        (__attribute__((address_space(3))) unsigned int*)lp,
        16, 0, 0);
}

struct ushort4s { unsigned short x, y, z, w; };

// ---------------- prep: norms + diag dist + fp32->bf16 + counter zeroing ----------------
__global__ __launch_bounds__(256) void taw_prep_kernel(
        const float* __restrict__ a, const float* __restrict__ p,
        float* __restrict__ ws) {
    const int i = blockIdx.x;
    const int t = threadIdx.x;
    if (i == 0 && t < 64) ((unsigned int*)ws)[1536 + t] = 0u;  // sum/cnt/done
    const float4* a4 = (const float4*)(a + (size_t)i * PD);
    const float4* p4 = (const float4*)(p + (size_t)i * PD);
    unsigned short* ah = (unsigned short*)((char*)ws + WS_AH_BYTES) + (size_t)i * PD;
    unsigned short* ph = (unsigned short*)((char*)ws + WS_PH_BYTES) + (size_t)i * PD;
    float sa = 0.f, sp = 0.f, dp = 0.f;
#pragma unroll
    for (int c = 0; c < 4; ++c) {
        const int e = c * 256 + t;
        float4 av = a4[e];
        float4 pv = p4[e];
        sa += av.x * av.x + av.y * av.y + av.z * av.z + av.w * av.w;
        sp += pv.x * pv.x + pv.y * pv.y + pv.z * pv.z + pv.w * pv.w;
        dp += av.x * pv.x + av.y * pv.y + av.z * pv.z + av.w * pv.w;
        ushort4s ab = {f2bf(av.x), f2bf(av.y), f2bf(av.z), f2bf(av.w)};
        ushort4s pb = {f2bf(pv.x), f2bf(pv.y), f2bf(pv.z), f2bf(pv.w)};
        *(ushort4s*)(ah + (size_t)e * 4) = ab;
        *(ushort4s*)(ph + (size_t)e * 4) = pb;
    }
#pragma unroll
    for (int off = 32; off > 0; off >>= 1) {
        sa += __shfl_down(sa, off, 64);
        sp += __shfl_down(sp, off, 64);
        dp += __shfl_down(dp, off, 64);
    }
    __shared__ float red[3][4];
    const int wave = t >> 6;
    if ((t & 63) == 0) { red[0][wave] = sa; red[1][wave] = sp; red[2][wave] = dp; }
    __syncthreads();
    if (t == 0) {
        sa = red[0][0] + red[0][1] + red[0][2] + red[0][3];
        sp = red[1][0] + red[1][1] + red[1][2] + red[1][3];
        dp = red[2][0] + red[2][1] + red[2][2] + red[2][3];
        float d2 = sa - 2.f * dp + sp;
        d2 = fmaxf(d2, 0.f);
        ws[F_SA + i] = sa;
        ws[F_SP + i] = sp;
        ws[F_DD + i] = (d2 == 0.f) ? 0.f : sqrtf(d2);
    }
}

// ---------------- fused GEMM + in-block K-reduce + epilogue + election finalize ------------
// grid (16,16), block 1024 = 16 waves. Wave w: kg = w>>2 (K-group, 1024 k each),
// quad = w&3 -> 16x16 quadrant (qm=quad>>1, qn=quad&1) of the 32x32 tile.
// Staging LDS (32 KB): stage[kg][arr][g][lane][8 bf16], g = kc*2 + rg
//   (rg = 16-row half, kc = 32-k chunk of the 64-k stage).
// Reduction LDS reuses the same 32 KB: red[kg][quad][lane][4 f32] (16 KB).
__global__ __launch_bounds__(1024) void taw_fused_kernel(float* __restrict__ ws,
                                                         float* __restrict__ out) {
    __shared__ __attribute__((aligned(16))) char shraw[32768];
    short* sbase = (short*)shraw;
    float* rbase = (float*)shraw;
    const unsigned short* ah = (const unsigned short*)((const char*)ws + WS_AH_BYTES);
    const unsigned short* ph = (const unsigned short*)((const char*)ws + WS_PH_BYTES);
    unsigned int* wsu = (unsigned int*)ws;

    const int t = threadIdx.x;
    const int lane = t & 63;
    const int w = t >> 6;
    const int kg = w >> 2;
    const int quad = w & 3;
    const int qm = quad >> 1, qn = quad & 1;
    const int i0 = blockIdx.y * 32;
    const int j0 = blockIdx.x * 32;
    const int kgbase = kg << 10;  // kg * 1024

    // short-offsets into stage: (kg,arr,g) -> (((kg*2+arr)*4)+g)*512
#define SG_OFF(KG, ARR, G) (((((KG) * 2 + (ARR)) * 4) + (G)) * 512)

    // Loader addresses for this wave (group g = quad): rg = quad&1, kc = quad>>1.
    const int lrow = ((quad & 1) << 4) + (lane & 15);
    const int lkof = ((quad >> 1) << 5) + ((lane >> 4) << 3);
    const unsigned short* agp = ah + (size_t)(i0 + lrow) * PD + kgbase + lkof;
    const unsigned short* pgp = ph + (size_t)(j0 + lrow) * PD + kgbase + lkof;
    short* sA = sbase + SG_OFF(kg, 0, quad);
    short* sB = sbase + SG_OFF(kg, 1, quad);

    floatx4 acc = {0.f, 0.f, 0.f, 0.f};
    const int lane8 = lane * 8;

    for (int st = 0; st < 16; ++st) {
        __syncthreads();  // previous stage's ds_reads done before overwrite
        load16_lds(agp + st * 64, sA);
        load16_lds(pgp + st * 64, sB);
        __syncthreads();  // staged data visible (vmcnt drain)
        short8 af0 = *(const short8*)(sbase + SG_OFF(kg, 0, qm) + lane8);
        short8 bf0 = *(const short8*)(sbase + SG_OFF(kg, 1, qn) + lane8);
        short8 af1 = *(const short8*)(sbase + SG_OFF(kg, 0, 2 + qm) + lane8);
        short8 bf1 = *(const short8*)(sbase + SG_OFF(kg, 1, 2 + qn) + lane8);
        acc = __builtin_amdgcn_mfma_f32_16x16x32_bf16(af0, bf0, acc, 0, 0, 0);
        acc = __builtin_amdgcn_mfma_f32_16x16x32_bf16(af1, bf1, acc, 0, 0, 0);
    }

    // Cross-K reduction through LDS (reuse staging memory).
    __syncthreads();  // all ds_reads of final stage done
    *(floatx4*)(rbase + (((kg * 4 + quad) * 64) + lane) * 4) = acc;
    __syncthreads();

    __shared__ float rs[4];
    __shared__ unsigned int rc[4];
    if (kg == 0) {
        floatx4 d = *(const floatx4*)(rbase + (((0 * 4 + quad) * 64) + lane) * 4);
#pragma unroll
        for (int k = 1; k < 4; ++k)
            d += *(const floatx4*)(rbase + (((k * 4 + quad) * 64) + lane) * 4);
        // C/D layout: col = lane&15, row = (lane>>4)*4 + r  [m89-verified]
        const int gj = j0 + qn * 16 + (lane & 15);
        const float spj = ws[F_SP + gj];
        float lsum = 0.f;
        unsigned int lcnt = 0;
#pragma unroll
        for (int r = 0; r < 4; ++r) {
            const int gi = i0 + qm * 16 + ((lane >> 4) << 2) + r;
            float d2 = ws[F_SA + gi] - 2.f * d[r] + spj;
            d2 = fmaxf(d2, 0.f);
            const float dist = (d2 == 0.f) ? 0.f : sqrtf(d2);
            const float v = (gi != gj) ? fmaxf(ws[F_DD + gi] - dist, 0.f) : 0.f;
            lsum += v;
            lcnt += (v > 1e-16f) ? 1u : 0u;
        }
#pragma unroll
        for (int off = 32; off > 0; off >>= 1) {
            lsum += __shfl_down(lsum, off, 64);
            lcnt += __shfl_down(lcnt, off, 64);
        }
        if (lane == 0) { rs[quad] = lsum; rc[quad] = lcnt; }
    }
    __syncthreads();
    if (t == 0) {
        atomicAdd(ws + F_SUM, rs[0] + rs[1] + rs[2] + rs[3]);
        atomicAdd(&wsu[F_CNT], rc[0] + rc[1] + rc[2] + rc[3]);
        __threadfence();
        if (atomicAdd(&wsu[F_DONE], 1u) == 255u) {  // trivial-tail election
            __threadfence();
            const float s = atomicAdd(ws + F_SUM, 0.0f);        // coherent read
            const unsigned int c = atomicAdd(&wsu[F_CNT], 0u);  // coherent read
            out[0] = (float)((double)s / ((double)c + 1e-16));
        }
    }
#undef SG_OFF
}

// ---------------- fallback single-pass fp32 GEMM (proven path) ----------------
__global__ __launch_bounds__(256) void taw_gemm_loss_kernel(
        const float* __restrict__ A, const float* __restrict__ P,
        float* __restrict__ ws) {
    __shared__ float as[32][34];
    __shared__ float bs[32][34];
    const int tx = threadIdx.x;
    const int ty = threadIdx.y;
    const int t = ty * 16 + tx;
    const int i0 = blockIdx.y * 32;
    const int j0 = blockIdx.x * 32;
    const int sr = t >> 3;
    const int sk = (t & 7) * 4;
    const float* aptr = A + (size_t)(i0 + sr) * PD + sk;
    const float* pptr = P + (size_t)(j0 + sr) * PD + sk;
    float c00 = 0.f, c01 = 0.f, c10 = 0.f, c11 = 0.f;
    for (int k0 = 0; k0 < PD; k0 += 32) {
        float4 av = *(const float4*)(aptr + k0);
        float4 pv = *(const float4*)(pptr + k0);
        __syncthreads();
        as[sk + 0][sr] = av.x; as[sk + 1][sr] = av.y;
        as[sk + 2][sr] = av.z; as[sk + 3][sr] = av.w;
        bs[sk + 0][sr] = pv.x; bs[sk + 1][sr] = pv.y;
        bs[sk + 2][sr] = pv.z; bs[sk + 3][sr] = pv.w;
        __syncthreads();
#pragma unroll
        for (int kk = 0; kk < 32; ++kk) {
            const float2 a2 = *(const float2*)&as[kk][2 * ty];
            const float2 b2 = *(const float2*)&bs[kk][2 * tx];
            c00 = fmaf(a2.x, b2.x, c00);
            c01 = fmaf(a2.x, b2.y, c01);
            c10 = fmaf(a2.y, b2.x, c10);
            c11 = fmaf(a2.y, b2.y, c11);
        }
    }
    const int i = i0 + 2 * ty;
    const int j = j0 + 2 * tx;
    float cvals[2][2] = {{c00, c01}, {c10, c11}};
    float lsum = 0.f;
    unsigned int lcnt = 0;
#pragma unroll
    for (int dr = 0; dr < 2; ++dr)
#pragma unroll
        for (int dc = 0; dc < 2; ++dc) {
            const int ii = i + dr, jj = j + dc;
            float d2 = ws[F_SA + ii] - 2.f * cvals[dr][dc] + ws[F_SP + jj];
            d2 = fmaxf(d2, 0.f);
            const float dist = (d2 == 0.f) ? 0.f : sqrtf(d2);
            const float v = (ii != jj) ? fmaxf(ws[F_DD + ii] - dist, 0.f) : 0.f;
            lsum += v;
            lcnt += (v > 1e-16f) ? 1u : 0u;
        }
#pragma unroll
    for (int off = 32; off > 0; off >>= 1) {
        lsum += __shfl_down(lsum, off, 64);
        lcnt += __shfl_down(lcnt, off, 64);
    }
    __shared__ float rsum[4];
    __shared__ unsigned int rcnt[4];
    if ((t & 63) == 0) { rsum[t >> 6] = lsum; rcnt[t >> 6] = lcnt; }
    __syncthreads();
    if (t == 0) {
        atomicAdd(ws + F_SUM, rsum[0] + rsum[1] + rsum[2] + rsum[3]);
        atomicAdd(((unsigned int*)ws) + F_CNT, rcnt[0] + rcnt[1] + rcnt[2] + rcnt[3]);
    }
}

__global__ void taw_finalize_kernel(const float* __restrict__ ws,
                                    float* __restrict__ out) {
    const double s = (double)ws[F_SUM];
    const double c = (double)(((const unsigned int*)ws)[F_CNT]);
    out[0] = (float)(s / (c + 1e-16));
}

extern "C" void kernel_launch(void* const* d_in, const int* in_sizes, int n_in,
                              void* d_out, int out_size, void* d_ws, size_t ws_size,
                              hipStream_t stream) {
    (void)in_sizes; (void)n_in; (void)out_size;
    const float* a = (const float*)d_in[0];
    const float* p = (const float*)d_in[1];
    float* out = (float*)d_out;
    float* ws = (float*)d_ws;

    taw_prep_kernel<<<PN, 256, 0, stream>>>(a, p, ws);
    if (ws_size >= WS_NEED) {
        taw_fused_kernel<<<dim3(16, 16), 1024, 0, stream>>>(ws, out);
    } else {
        taw_gemm_loss_kernel<<<dim3(16, 16), dim3(16, 16), 0, stream>>>(a, p, ws);
        taw_finalize_kernel<<<1, 1, 0, stream>>>(ws, out);
    }
}

// Round 6
// 98.110 us; speedup vs baseline: 1.0042x; 1.0042x over previous
//
#include <hip/hip_runtime.h>
#include <math.h>

// Problem constants (from reference: N=512, D=4096, fp32).
#define PN 512
#define PD 4096

// Fused GEMM config: 32x32 tile/block, full K in-block.
#define NKG 2                        // K-groups (waves 0-3 -> kg0, 4-7 -> kg1)
#define BKST 128                     // k per LDS stage
#define NST (PD / NKG / BKST)        // 16 stages per kg

// ws float-index layout:
//   [0,512) sa | [512,1024) sp | [1024,1536) dd
//   1536 sum(f32) | 1537 cnt(u32) | 1538 done(u32)
//   byte 8192:      ah bf16 [512][4096]  (4 MB)
//   byte 8192+4MB:  ph bf16 [512][4096]  (4 MB)
#define F_SA 0
#define F_SP 512
#define F_DD 1024
#define F_SUM 1536
#define F_CNT 1537
#define F_DONE 1538
#define WS_AH_BYTES 8192
#define WS_PH_BYTES (8192 + 4194304)
#define WS_NEED ((size_t)(8192 + 2 * 4194304))

typedef __attribute__((ext_vector_type(8))) short short8;
typedef __attribute__((ext_vector_type(4))) float floatx4;

static __device__ __forceinline__ unsigned short f2bf(float x) {
    unsigned int u = __float_as_uint(x);
    u += 0x7fffu + ((u >> 16) & 1u);
    return (unsigned short)(u >> 16);
}

static __device__ __forceinline__ void load16_lds(const void* gp, void* lp) {
    __builtin_amdgcn_global_load_lds(
        (const __attribute__((address_space(1))) unsigned int*)gp,
        (__attribute__((address_space(3))) unsigned int*)lp,
        16, 0, 0);
}

struct ushort4s { unsigned short x, y, z, w; };

// ---------------- prep: norms + diag dist + fp32->bf16 + counter zeroing ----------------
__global__ __launch_bounds__(256) void taw_prep_kernel(
        const float* __restrict__ a, const float* __restrict__ p,
        float* __restrict__ ws) {
    const int i = blockIdx.x;
    const int t = threadIdx.x;
    if (i == 0 && t < 64) ((unsigned int*)ws)[1536 + t] = 0u;  // sum/cnt/done
    const float4* a4 = (const float4*)(a + (size_t)i * PD);
    const float4* p4 = (const float4*)(p + (size_t)i * PD);
    unsigned short* ah = (unsigned short*)((char*)ws + WS_AH_BYTES) + (size_t)i * PD;
    unsigned short* ph = (unsigned short*)((char*)ws + WS_PH_BYTES) + (size_t)i * PD;
    float sa = 0.f, sp = 0.f, dp = 0.f;
#pragma unroll
    for (int c = 0; c < 4; ++c) {
        const int e = c * 256 + t;
        float4 av = a4[e];
        float4 pv = p4[e];
        sa += av.x * av.x + av.y * av.y + av.z * av.z + av.w * av.w;
        sp += pv.x * pv.x + pv.y * pv.y + pv.z * pv.z + pv.w * pv.w;
        dp += av.x * pv.x + av.y * pv.y + av.z * pv.z + av.w * pv.w;
        ushort4s ab = {f2bf(av.x), f2bf(av.y), f2bf(av.z), f2bf(av.w)};
        ushort4s pb = {f2bf(pv.x), f2bf(pv.y), f2bf(pv.z), f2bf(pv.w)};
        *(ushort4s*)(ah + (size_t)e * 4) = ab;
        *(ushort4s*)(ph + (size_t)e * 4) = pb;
    }
#pragma unroll
    for (int off = 32; off > 0; off >>= 1) {
        sa += __shfl_down(sa, off, 64);
        sp += __shfl_down(sp, off, 64);
        dp += __shfl_down(dp, off, 64);
    }
    __shared__ float red[3][4];
    const int wave = t >> 6;
    if ((t & 63) == 0) { red[0][wave] = sa; red[1][wave] = sp; red[2][wave] = dp; }
    __syncthreads();
    if (t == 0) {
        sa = red[0][0] + red[0][1] + red[0][2] + red[0][3];
        sp = red[1][0] + red[1][1] + red[1][2] + red[1][3];
        dp = red[2][0] + red[2][1] + red[2][2] + red[2][3];
        float d2 = sa - 2.f * dp + sp;
        d2 = fmaxf(d2, 0.f);
        ws[F_SA + i] = sa;
        ws[F_SP + i] = sp;
        ws[F_DD + i] = (d2 == 0.f) ? 0.f : sqrtf(d2);
    }
}

// ---------------- fused: full-K-in-block GEMM + epilogue + atomic-only finalize --------------
// grid (16,16), block 512 = 8 waves. Wave w: kg = w>>2 (K-half, 2048 each),
// quad q = w&3 -> 16x16 quadrant (qm=q>>1, qn=q&1) of the 32x32 tile.
// LDS lds[buf][kg][arr][g][lane][8]: group g = s*2 + rg holds rows rg*16+(lane&15),
// k-chunk s*32+(lane>>4)*8 — exact MFMA A/B fragment order (proven R3/R5).
// Double-buffered: one barrier per stage; loads for st+1 fly during compute of st.
// NO __threadfence anywhere (R4/R5 post-mortem: device fences blow L2 locality).
__global__ __launch_bounds__(512) void taw_fused_kernel(float* __restrict__ ws,
                                                        float* __restrict__ out) {
    __shared__ short lds[2][NKG][2][8][64][8];  // 64 KB
    const unsigned short* ah = (const unsigned short*)((const char*)ws + WS_AH_BYTES);
    const unsigned short* ph = (const unsigned short*)((const char*)ws + WS_PH_BYTES);
    unsigned int* wsu = (unsigned int*)ws;

    const int t = threadIdx.x;
    const int lane = t & 63;
    const int w = t >> 6;
    const int kg = w >> 2;
    const int q = w & 3;
    const int qm = q >> 1, qn = q & 1;
    const int i0 = blockIdx.y * 32;
    const int j0 = blockIdx.x * 32;
    const int kgbase = kg * (PD / NKG);  // kg * 2048

    // Loader: wave q stages groups {2q, 2q+1} of both arrays for its kg.
    // For g = 2q+rg: s = q, rg in {0,1}.
    const int koff = kgbase + q * 32 + ((lane >> 4) << 3);
    const unsigned short* agp0 = ah + (size_t)(i0 + (lane & 15)) * PD + koff;       // rg=0
    const unsigned short* agp1 = ah + (size_t)(i0 + 16 + (lane & 15)) * PD + koff;  // rg=1
    const unsigned short* pgp0 = ph + (size_t)(j0 + (lane & 15)) * PD + koff;
    const unsigned short* pgp1 = ph + (size_t)(j0 + 16 + (lane & 15)) * PD + koff;

    floatx4 acc = {0.f, 0.f, 0.f, 0.f};
    int buf = 0;

    // Prologue: stage 0 into buf 0.
    load16_lds(agp0, &lds[0][kg][0][2 * q + 0][0][0]);
    load16_lds(agp1, &lds[0][kg][0][2 * q + 1][0][0]);
    load16_lds(pgp0, &lds[0][kg][1][2 * q + 0][0][0]);
    load16_lds(pgp1, &lds[0][kg][1][2 * q + 1][0][0]);

    for (int st = 0; st < NST; ++st) {
        __syncthreads();  // drains vmcnt: stage-st data visible; prior reads of buf^1 done
        if (st + 1 < NST) {
            const int kb = (st + 1) * BKST;
            load16_lds(agp0 + kb, &lds[buf ^ 1][kg][0][2 * q + 0][0][0]);
            load16_lds(agp1 + kb, &lds[buf ^ 1][kg][0][2 * q + 1][0][0]);
            load16_lds(pgp0 + kb, &lds[buf ^ 1][kg][1][2 * q + 0][0][0]);
            load16_lds(pgp1 + kb, &lds[buf ^ 1][kg][1][2 * q + 1][0][0]);
        }
#pragma unroll
        for (int s = 0; s < 4; ++s) {
            short8 af = *(const short8*)&lds[buf][kg][0][s * 2 + qm][lane][0];
            short8 bf = *(const short8*)&lds[buf][kg][1][s * 2 + qn][lane][0];
            acc = __builtin_amdgcn_mfma_f32_16x16x32_bf16(af, bf, acc, 0, 0, 0);
        }
        buf ^= 1;
    }

    // Cross-kg combine through LDS (reuse staging memory; 4 KB).
    __syncthreads();  // final stage's ds_reads done before overwrite
    float* fred = (float*)&lds[0][0][0][0][0][0];
    if (kg == 1) *(floatx4*)(fred + (q * 64 + lane) * 4) = acc;
    __syncthreads();

    __shared__ float rs[4];
    __shared__ unsigned int rc[4];
    if (kg == 0) {
        acc += *(const floatx4*)(fred + (q * 64 + lane) * 4);
        // C/D layout: col = lane&15, row = (lane>>4)*4 + r  [m89-verified]
        const int gj = j0 + qn * 16 + (lane & 15);
        const float spj = ws[F_SP + gj];
        float lsum = 0.f;
        unsigned int lcnt = 0;
#pragma unroll
        for (int r = 0; r < 4; ++r) {
            const int gi = i0 + qm * 16 + ((lane >> 4) << 2) + r;
            float d2 = ws[F_SA + gi] - 2.f * acc[r] + spj;
            d2 = fmaxf(d2, 0.f);
            const float dist = (d2 == 0.f) ? 0.f : sqrtf(d2);
            const float v = (gi != gj) ? fmaxf(ws[F_DD + gi] - dist, 0.f) : 0.f;
            lsum += v;
            lcnt += (v > 1e-16f) ? 1u : 0u;
        }
#pragma unroll
        for (int off = 32; off > 0; off >>= 1) {
            lsum += __shfl_down(lsum, off, 64);
            lcnt += __shfl_down(lcnt, off, 64);
        }
        if (lane == 0) { rs[q] = lsum; rc[q] = lcnt; }
    }
    __syncthreads();
    if (t == 0) {
        // Atomic-only cross-block protocol: atomics execute at the device
        // coherence point; consuming the returned values forces retirement
        // (s_waitcnt) before the election bump -> ordering without fences.
        const float oldsum = atomicAdd(ws + F_SUM, rs[0] + rs[1] + rs[2] + rs[3]);
        const unsigned int oldcnt = atomicAdd(&wsu[F_CNT], rc[0] + rc[1] + rc[2] + rc[3]);
        unsigned int dep = __float_as_uint(oldsum) | oldcnt;
        asm volatile("" : "+v"(dep));  // opaque: keeps the data dependency alive
        if (atomicAdd(&wsu[F_DONE], 1u + (dep & 0u)) == 255u) {
            const float s = atomicAdd(ws + F_SUM, 0.0f);        // coherent read
            const unsigned int c = atomicAdd(&wsu[F_CNT], 0u);  // coherent read
            out[0] = (float)((double)s / ((double)c + 1e-16));
        }
    }
}

// ---------------- fallback single-pass fp32 GEMM (proven path) ----------------
__global__ __launch_bounds__(256) void taw_gemm_loss_kernel(
        const float* __restrict__ A, const float* __restrict__ P,
        float* __restrict__ ws) {
    __shared__ float as[32][34];
    __shared__ float bs[32][34];
    const int tx = threadIdx.x;
    const int ty = threadIdx.y;
    const int t = ty * 16 + tx;
    const int i0 = blockIdx.y * 32;
    const int j0 = blockIdx.x * 32;
    const int sr = t >> 3;
    const int sk = (t & 7) * 4;
    const float* aptr = A + (size_t)(i0 + sr) * PD + sk;
    const float* pptr = P + (size_t)(j0 + sr) * PD + sk;
    float c00 = 0.f, c01 = 0.f, c10 = 0.f, c11 = 0.f;
    for (int k0 = 0; k0 < PD; k0 += 32) {
        float4 av = *(const float4*)(aptr + k0);
        float4 pv = *(const float4*)(pptr + k0);
        __syncthreads();
        as[sk + 0][sr] = av.x; as[sk + 1][sr] = av.y;
        as[sk + 2][sr] = av.z; as[sk + 3][sr] = av.w;
        bs[sk + 0][sr] = pv.x; bs[sk + 1][sr] = pv.y;
        bs[sk + 2][sr] = pv.z; bs[sk + 3][sr] = pv.w;
        __syncthreads();
#pragma unroll
        for (int kk = 0; kk < 32; ++kk) {
            const float2 a2 = *(const float2*)&as[kk][2 * ty];
            const float2 b2 = *(const float2*)&bs[kk][2 * tx];
            c00 = fmaf(a2.x, b2.x, c00);
            c01 = fmaf(a2.x, b2.y, c01);
            c10 = fmaf(a2.y, b2.x, c10);
            c11 = fmaf(a2.y, b2.y, c11);
        }
    }
    const int i = i0 + 2 * ty;
    const int j = j0 + 2 * tx;
    float cvals[2][2] = {{c00, c01}, {c10, c11}};
    float lsum = 0.f;
    unsigned int lcnt = 0;
#pragma unroll
    for (int dr = 0; dr < 2; ++dr)
#pragma unroll
        for (int dc = 0; dc < 2; ++dc) {
            const int ii = i + dr, jj = j + dc;
            float d2 = ws[F_SA + ii] - 2.f * cvals[dr][dc] + ws[F_SP + jj];
            d2 = fmaxf(d2, 0.f);
            const float dist = (d2 == 0.f) ? 0.f : sqrtf(d2);
            const float v = (ii != jj) ? fmaxf(ws[F_DD + ii] - dist, 0.f) : 0.f;
            lsum += v;
            lcnt += (v > 1e-16f) ? 1u : 0u;
        }
#pragma unroll
    for (int off = 32; off > 0; off >>= 1) {
        lsum += __shfl_down(lsum, off, 64);
        lcnt += __shfl_down(lcnt, off, 64);
    }
    __shared__ float rsum[4];
    __shared__ unsigned int rcnt[4];
    if ((t & 63) == 0) { rsum[t >> 6] = lsum; rcnt[t >> 6] = lcnt; }
    __syncthreads();
    if (t == 0) {
        atomicAdd(ws + F_SUM, rsum[0] + rsum[1] + rsum[2] + rsum[3]);
        atomicAdd(((unsigned int*)ws) + F_CNT, rcnt[0] + rcnt[1] + rcnt[2] + rcnt[3]);
    }
}

__global__ void taw_finalize_kernel(const float* __restrict__ ws,
                                    float* __restrict__ out) {
    const double s = (double)ws[F_SUM];
    const double c = (double)(((const unsigned int*)ws)[F_CNT]);
    out[0] = (float)(s / (c + 1e-16));
}

extern "C" void kernel_launch(void* const* d_in, const int* in_sizes, int n_in,
                              void* d_out, int out_size, void* d_ws, size_t ws_size,
                              hipStream_t stream) {
    (void)in_sizes; (void)n_in; (void)out_size;
    const float* a = (const float*)d_in[0];
    const float* p = (const float*)d_in[1];
    float* out = (float*)d_out;
    float* ws = (float*)d_ws;

    taw_prep_kernel<<<PN, 256, 0, stream>>>(a, p, ws);
    if (ws_size >= WS_NEED) {
        taw_fused_kernel<<<dim3(16, 16), 512, 0, stream>>>(ws, out);
    } else {
        taw_gemm_loss_kernel<<<dim3(16, 16), dim3(16, 16), 0, stream>>>(a, p, ws);
        taw_finalize_kernel<<<1, 1, 0, stream>>>(ws, out);
    }
}

// Round 7
// 90.510 us; speedup vs baseline: 1.0885x; 1.0840x over previous
//
#include <hip/hip_runtime.h>
#include <math.h>

// Problem constants (from reference: N=512, D=4096, fp32).
#define PN 512
#define PD 4096

// bf16 MFMA split-K config (R3 proven: 89.6 us total)
#define KSZ 8
#define KCHUNK (PD / KSZ)     // 512
#define BK 64                 // K per LDS stage
#define NSTAGE (KCHUNK / BK)  // 8

// ws float-index layout:
//   [0,512) sa | [512,1024) sp | [1024,1536) dd
//   1536 sum(f32) | 1537 cnt(u32) | 1538 done(u32)
//   byte 8192:            ah bf16 [512][4096]  (4 MB)
//   byte 8192+4MB:        ph bf16 [512][4096]  (4 MB)
//   float WS_PART_FLOAT:  split-K partials f32 [KSZ][512][512] (8 MB)
#define F_SA 0
#define F_SP 512
#define F_DD 1024
#define F_SUM 1536
#define F_CNT 1537
#define F_DONE 1538
#define WS_AH_BYTES 8192
#define WS_PH_BYTES (8192 + 4194304)
#define WS_PART_FLOAT 2099200  // (8192 + 2*4194304)/4
#define WS_NEED ((size_t)WS_PART_FLOAT * 4 + (size_t)KSZ * PN * PN * 4)

typedef __attribute__((ext_vector_type(8))) short short8;
typedef __attribute__((ext_vector_type(4))) float floatx4;

static __device__ __forceinline__ unsigned short f2bf(float x) {
    unsigned int u = __float_as_uint(x);
    u += 0x7fffu + ((u >> 16) & 1u);
    return (unsigned short)(u >> 16);
}

static __device__ __forceinline__ void load16_lds(const void* gp, void* lp) {
    __builtin_amdgcn_global_load_lds(
        (const __attribute__((address_space(1))) unsigned int*)gp,
        (__attribute__((address_space(3))) unsigned int*)lp,
        16, 0, 0);
}

struct ushort4s { unsigned short x, y, z, w; };

// ---------------- prep: norms + diag dist + fp32->bf16 + counter zeroing ----------------
__global__ __launch_bounds__(256) void taw_prep_kernel(
        const float* __restrict__ a, const float* __restrict__ p,
        float* __restrict__ ws) {
    const int i = blockIdx.x;
    const int t = threadIdx.x;
    if (i == 0 && t < 64) ((unsigned int*)ws)[1536 + t] = 0u;  // sum/cnt/done
    const float4* a4 = (const float4*)(a + (size_t)i * PD);
    const float4* p4 = (const float4*)(p + (size_t)i * PD);
    unsigned short* ah = (unsigned short*)((char*)ws + WS_AH_BYTES) + (size_t)i * PD;
    unsigned short* ph = (unsigned short*)((char*)ws + WS_PH_BYTES) + (size_t)i * PD;
    float sa = 0.f, sp = 0.f, dp = 0.f;
#pragma unroll
    for (int c = 0; c < 4; ++c) {
        const int e = c * 256 + t;
        float4 av = a4[e];
        float4 pv = p4[e];
        sa += av.x * av.x + av.y * av.y + av.z * av.z + av.w * av.w;
        sp += pv.x * pv.x + pv.y * pv.y + pv.z * pv.z + pv.w * pv.w;
        dp += av.x * pv.x + av.y * pv.y + av.z * pv.z + av.w * pv.w;
        ushort4s ab = {f2bf(av.x), f2bf(av.y), f2bf(av.z), f2bf(av.w)};
        ushort4s pb = {f2bf(pv.x), f2bf(pv.y), f2bf(pv.z), f2bf(pv.w)};
        *(ushort4s*)(ah + (size_t)e * 4) = ab;
        *(ushort4s*)(ph + (size_t)e * 4) = pb;
    }
#pragma unroll
    for (int off = 32; off > 0; off >>= 1) {
        sa += __shfl_down(sa, off, 64);
        sp += __shfl_down(sp, off, 64);
        dp += __shfl_down(dp, off, 64);
    }
    __shared__ float red[3][4];
    const int wave = t >> 6;
    if ((t & 63) == 0) { red[0][wave] = sa; red[1][wave] = sp; red[2][wave] = dp; }
    __syncthreads();
    if (t == 0) {
        sa = red[0][0] + red[0][1] + red[0][2] + red[0][3];
        sp = red[1][0] + red[1][1] + red[1][2] + red[1][3];
        dp = red[2][0] + red[2][1] + red[2][2] + red[2][3];
        float d2 = sa - 2.f * dp + sp;
        d2 = fmaxf(d2, 0.f);
        ws[F_SA + i] = sa;
        ws[F_SP + i] = sp;
        ws[F_DD + i] = (d2 == 0.f) ? 0.f : sqrtf(d2);
    }
}

// ---------------- bf16 MFMA split-K GEMM (R3-exact): 64x64 tile, Kchunk 512 ----------------
// grid (8, 8, KSZ), block 256 (4 waves; wave w -> 32x32 quadrant (w>>1, w&1)).
// LDS in fragment order: lds[A/B][group g][lane][8 bf16].
__global__ __launch_bounds__(256) void taw_mfma_kernel(float* __restrict__ ws) {
    __shared__ short lds[2][8][64][8];  // 16 KB
    const unsigned short* ah = (const unsigned short*)((const char*)ws + WS_AH_BYTES);
    const unsigned short* ph = (const unsigned short*)((const char*)ws + WS_PH_BYTES);
    const int t = threadIdx.x;
    const int lane = t & 63;
    const int w = t >> 6;
    const int wm = w >> 1, wn = w & 1;
    const int i0 = blockIdx.y * 64;
    const int j0 = blockIdx.x * 64;
    const int kz = blockIdx.z * KCHUNK;

    floatx4 acc[2][2] = {{{0.f, 0.f, 0.f, 0.f}, {0.f, 0.f, 0.f, 0.f}},
                         {{0.f, 0.f, 0.f, 0.f}, {0.f, 0.f, 0.f, 0.f}}};

    for (int st = 0; st < NSTAGE; ++st) {
        const int kb = kz + st * BK;
        __syncthreads();
#pragma unroll
        for (int q = 0; q < 2; ++q) {
            const int g = 2 * w + q;
            const int row = ((g & 3) << 4) + (lane & 15);
            const int kk = kb + ((((g >> 2) << 2) + (lane >> 4)) << 3);
            load16_lds(ah + (size_t)(i0 + row) * PD + kk, &lds[0][g][0][0]);
            load16_lds(ph + (size_t)(j0 + row) * PD + kk, &lds[1][g][0][0]);
        }
        __syncthreads();
#pragma unroll
        for (int s2 = 0; s2 < 2; ++s2) {
            short8 af0 = *(const short8*)&lds[0][s2 * 4 + wm * 2 + 0][lane][0];
            short8 af1 = *(const short8*)&lds[0][s2 * 4 + wm * 2 + 1][lane][0];
            short8 bf0 = *(const short8*)&lds[1][s2 * 4 + wn * 2 + 0][lane][0];
            short8 bf1 = *(const short8*)&lds[1][s2 * 4 + wn * 2 + 1][lane][0];
            acc[0][0] = __builtin_amdgcn_mfma_f32_16x16x32_bf16(af0, bf0, acc[0][0], 0, 0, 0);
            acc[0][1] = __builtin_amdgcn_mfma_f32_16x16x32_bf16(af0, bf1, acc[0][1], 0, 0, 0);
            acc[1][0] = __builtin_amdgcn_mfma_f32_16x16x32_bf16(af1, bf0, acc[1][0], 0, 0, 0);
            acc[1][1] = __builtin_amdgcn_mfma_f32_16x16x32_bf16(af1, bf1, acc[1][1], 0, 0, 0);
        }
    }

    // C/D layout: col=lane&15, row=(lane>>4)*4+reg [m89-verified]
    float* part = ws + WS_PART_FLOAT + (size_t)blockIdx.z * (PN * PN);
    const int jj = j0 + wn * 32 + (lane & 15);
    const int ib = i0 + wm * 32 + ((lane >> 4) << 2);
#pragma unroll
    for (int rm = 0; rm < 2; ++rm)
#pragma unroll
        for (int rn = 0; rn < 2; ++rn)
#pragma unroll
            for (int r = 0; r < 4; ++r)
                part[(size_t)(ib + rm * 16 + r) * PN + jj + rn * 16] = acc[rm][rn][r];
}

// ---------------- reduce partials + epilogue + election finalize ----------------
// 256 blocks x 256 threads; tiny per-block work -> negligible straggler/election tail.
__global__ __launch_bounds__(256) void taw_reduce_kernel(float* __restrict__ ws,
                                                         float* __restrict__ out) {
    unsigned int* wsu = (unsigned int*)ws;
    const int g = blockIdx.x * 256 + threadIdx.x;  // one float4 of the 512x512 dot
    const float4* part4 = (const float4*)(ws + WS_PART_FLOAT);
    float4 dot = part4[g];
#pragma unroll
    for (int ks = 1; ks < KSZ; ++ks) {
        const float4 v = part4[((size_t)ks << 16) + g];
        dot.x += v.x; dot.y += v.y; dot.z += v.z; dot.w += v.w;
    }
    const int flat = g << 2;
    const int i = flat >> 9;
    const int j = flat & 511;
    const float sa = ws[F_SA + i];
    const float dd = ws[F_DD + i];
    const float4 sp4 = *(const float4*)(ws + F_SP + j);
    const float dotr[4] = {dot.x, dot.y, dot.z, dot.w};
    const float spr[4] = {sp4.x, sp4.y, sp4.z, sp4.w};
    float lsum = 0.f;
    unsigned int lcnt = 0;
#pragma unroll
    for (int c = 0; c < 4; ++c) {
        const int jj = j + c;
        float d2 = sa - 2.f * dotr[c] + spr[c];
        d2 = fmaxf(d2, 0.f);
        const float dist = (d2 == 0.f) ? 0.f : sqrtf(d2);
        const float v = (i != jj) ? fmaxf(dd - dist, 0.f) : 0.f;
        lsum += v;
        lcnt += (v > 1e-16f) ? 1u : 0u;
    }
#pragma unroll
    for (int off = 32; off > 0; off >>= 1) {
        lsum += __shfl_down(lsum, off, 64);
        lcnt += __shfl_down(lcnt, off, 64);
    }
    __shared__ float rsum[4];
    __shared__ unsigned int rcnt[4];
    const int t = threadIdx.x;
    if ((t & 63) == 0) { rsum[t >> 6] = lsum; rcnt[t >> 6] = lcnt; }
    __syncthreads();
    if (t == 0) {
        // Atomic-only protocol: atomics execute at the device coherence point;
        // consuming returned values forces retirement before the DONE bump.
        const float oldsum = atomicAdd(ws + F_SUM, rsum[0] + rsum[1] + rsum[2] + rsum[3]);
        const unsigned int oldcnt = atomicAdd(&wsu[F_CNT],
                                              rcnt[0] + rcnt[1] + rcnt[2] + rcnt[3]);
        unsigned int dep = __float_as_uint(oldsum) | oldcnt;
        asm volatile("" : "+v"(dep));  // opaque: keep the data dependency alive
        if (atomicAdd(&wsu[F_DONE], 1u + (dep & 0u)) == 255u) {
            const float s = atomicAdd(ws + F_SUM, 0.0f);        // coherent read
            const unsigned int c = atomicAdd(&wsu[F_CNT], 0u);  // coherent read
            out[0] = (float)((double)s / ((double)c + 1e-16));
        }
    }
}

// ---------------- fallback single-pass fp32 GEMM (proven path) ----------------
__global__ __launch_bounds__(256) void taw_gemm_loss_kernel(
        const float* __restrict__ A, const float* __restrict__ P,
        float* __restrict__ ws) {
    __shared__ float as[32][34];
    __shared__ float bs[32][34];
    const int tx = threadIdx.x;
    const int ty = threadIdx.y;
    const int t = ty * 16 + tx;
    const int i0 = blockIdx.y * 32;
    const int j0 = blockIdx.x * 32;
    const int sr = t >> 3;
    const int sk = (t & 7) * 4;
    const float* aptr = A + (size_t)(i0 + sr) * PD + sk;
    const float* pptr = P + (size_t)(j0 + sr) * PD + sk;
    float c00 = 0.f, c01 = 0.f, c10 = 0.f, c11 = 0.f;
    for (int k0 = 0; k0 < PD; k0 += 32) {
        float4 av = *(const float4*)(aptr + k0);
        float4 pv = *(const float4*)(pptr + k0);
        __syncthreads();
        as[sk + 0][sr] = av.x; as[sk + 1][sr] = av.y;
        as[sk + 2][sr] = av.z; as[sk + 3][sr] = av.w;
        bs[sk + 0][sr] = pv.x; bs[sk + 1][sr] = pv.y;
        bs[sk + 2][sr] = pv.z; bs[sk + 3][sr] = pv.w;
        __syncthreads();
#pragma unroll
        for (int kk = 0; kk < 32; ++kk) {
            const float2 a2 = *(const float2*)&as[kk][2 * ty];
            const float2 b2 = *(const float2*)&bs[kk][2 * tx];
            c00 = fmaf(a2.x, b2.x, c00);
            c01 = fmaf(a2.x, b2.y, c01);
            c10 = fmaf(a2.y, b2.x, c10);
            c11 = fmaf(a2.y, b2.y, c11);
        }
    }
    const int i = i0 + 2 * ty;
    const int j = j0 + 2 * tx;
    float cvals[2][2] = {{c00, c01}, {c10, c11}};
    float lsum = 0.f;
    unsigned int lcnt = 0;
#pragma unroll
    for (int dr = 0; dr < 2; ++dr)
#pragma unroll
        for (int dc = 0; dc < 2; ++dc) {
            const int ii = i + dr, jj = j + dc;
            float d2 = ws[F_SA + ii] - 2.f * cvals[dr][dc] + ws[F_SP + jj];
            d2 = fmaxf(d2, 0.f);
            const float dist = (d2 == 0.f) ? 0.f : sqrtf(d2);
            const float v = (ii != jj) ? fmaxf(ws[F_DD + ii] - dist, 0.f) : 0.f;
            lsum += v;
            lcnt += (v > 1e-16f) ? 1u : 0u;
        }
#pragma unroll
    for (int off = 32; off > 0; off >>= 1) {
        lsum += __shfl_down(lsum, off, 64);
        lcnt += __shfl_down(lcnt, off, 64);
    }
    __shared__ float rsum[4];
    __shared__ unsigned int rcnt[4];
    if ((t & 63) == 0) { rsum[t >> 6] = lsum; rcnt[t >> 6] = lcnt; }
    __syncthreads();
    if (t == 0) {
        atomicAdd(ws + F_SUM, rsum[0] + rsum[1] + rsum[2] + rsum[3]);
        atomicAdd(((unsigned int*)ws) + F_CNT, rcnt[0] + rcnt[1] + rcnt[2] + rcnt[3]);
    }
}

__global__ void taw_finalize_kernel(const float* __restrict__ ws,
                                    float* __restrict__ out) {
    const double s = (double)ws[F_SUM];
    const double c = (double)(((const unsigned int*)ws)[F_CNT]);
    out[0] = (float)(s / (c + 1e-16));
}

extern "C" void kernel_launch(void* const* d_in, const int* in_sizes, int n_in,
                              void* d_out, int out_size, void* d_ws, size_t ws_size,
                              hipStream_t stream) {
    (void)in_sizes; (void)n_in; (void)out_size;
    const float* a = (const float*)d_in[0];
    const float* p = (const float*)d_in[1];
    float* out = (float*)d_out;
    float* ws = (float*)d_ws;

    taw_prep_kernel<<<PN, 256, 0, stream>>>(a, p, ws);
    if (ws_size >= WS_NEED) {
        taw_mfma_kernel<<<dim3(8, 8, KSZ), 256, 0, stream>>>(ws);
        taw_reduce_kernel<<<256, 256, 0, stream>>>(ws, out);
    } else {
        taw_gemm_loss_kernel<<<dim3(16, 16), dim3(16, 16), 0, stream>>>(a, p, ws);
        taw_finalize_kernel<<<1, 1, 0, stream>>>(ws, out);
    }
}